// Round 3
// baseline (130.694 us; speedup 1.0000x reference)
//
#include <hip/hip_runtime.h>
#include <math.h>

#define BB 8
#define NN 2048
#define FF 128
#define LALPHA 0.2f

#define CH 64
#define NCH (NN / CH)   // 32

#define WT_STRIDE 132   // 128 + 4 pad
#define XT_STRIDE 18    // 16 + 2 pad

// ---------------- K1: h = x @ W^T, si = h.a1, sj = h.a2 (+ zero cnt) ----------------
__global__ __launch_bounds__(256, 2)
void k1_h(const float* __restrict__ x, const float* __restrict__ W,
          const float* __restrict__ a, float* __restrict__ h,
          float* __restrict__ si, float* __restrict__ sj, int* __restrict__ cnt)
{
    __shared__ float Wt[FF * WT_STRIDE];
    __shared__ float xsT[FF * XT_STRIDE];
    const int t = threadIdx.x;
    const int row0 = blockIdx.x * 16;

    if (blockIdx.x == 0 && t < BB * NCH) cnt[t] = 0;   // 256 bucket counters

    for (int kk = t; kk < FF * FF; kk += 256) {
        int o = kk >> 7, f = kk & (FF - 1);
        Wt[f * WT_STRIDE + o] = W[kk];
    }
    for (int kk = t; kk < 16 * FF; kk += 256) {
        int r = kk >> 7, f = kk & (FF - 1);
        xsT[f * XT_STRIDE + r] = x[(row0 + r) * FF + f];
    }
    __syncthreads();

    const int oq = (t & 31) << 2;
    const int rp = t >> 5;
    float a00 = 0.f, a01 = 0.f, a02 = 0.f, a03 = 0.f;
    float a10 = 0.f, a11 = 0.f, a12 = 0.f, a13 = 0.f;
#pragma unroll 8
    for (int f = 0; f < FF; ++f) {
        float2 xv = *(const float2*)&xsT[f * XT_STRIDE + (rp << 1)];
        float4 wv = *(const float4*)&Wt[f * WT_STRIDE + oq];
        a00 += xv.x * wv.x; a01 += xv.x * wv.y; a02 += xv.x * wv.z; a03 += xv.x * wv.w;
        a10 += xv.y * wv.x; a11 += xv.y * wv.y; a12 += xv.y * wv.z; a13 += xv.y * wv.w;
    }
    const int r0 = row0 + (rp << 1), r1 = r0 + 1;
    *(float4*)&h[r0 * FF + oq] = make_float4(a00, a01, a02, a03);
    *(float4*)&h[r1 * FF + oq] = make_float4(a10, a11, a12, a13);

    const float4 a1v = *(const float4*)&a[oq];
    const float4 a2v = *(const float4*)&a[FF + oq];
    float s10 = a00 * a1v.x + a01 * a1v.y + a02 * a1v.z + a03 * a1v.w;
    float s11 = a10 * a1v.x + a11 * a1v.y + a12 * a1v.z + a13 * a1v.w;
    float s20 = a00 * a2v.x + a01 * a2v.y + a02 * a2v.z + a03 * a2v.w;
    float s21 = a10 * a2v.x + a11 * a2v.y + a12 * a2v.z + a13 * a2v.w;
#pragma unroll
    for (int off = 16; off >= 1; off >>= 1) {
        s10 += __shfl_down(s10, off, 32);
        s11 += __shfl_down(s11, off, 32);
        s20 += __shfl_down(s20, off, 32);
        s21 += __shfl_down(s21, off, 32);
    }
    if ((t & 31) == 0) {
        si[r0] = s10; si[r1] = s11;
        sj[r0] = s20; sj[r1] = s21;
    }
}

// ---------------- K2: rank-sort sj per batch ----------------
// grid = B*8 blocks, 1024 threads. Block = (batch, segment of 256 elems).
// Each element's rank computed by 4 threads (512-j slices), shfl-reduced.
__global__ __launch_bounds__(1024)
void k2_rank(const float* __restrict__ sj, float* __restrict__ keys, int* __restrict__ sidx)
{
    __shared__ float lk[NN];
    const int b = blockIdx.x >> 3;
    const int s = blockIdx.x & 7;
    const int t = threadIdx.x;
    for (int j = t; j < NN; j += 1024) lk[j] = sj[b * NN + j];
    __syncthreads();

    const int e = s * 256 + (t >> 2);   // element index in batch
    const int slice = t & 3;
    const float ki = lk[e];
    const float4* lk4 = (const float4*)lk;
    int r = 0;
    const int q0 = slice * 128;
#pragma unroll 8
    for (int q = q0; q < q0 + 128; ++q) {
        float4 v = lk4[q];
        int j = q << 2;
        r += (v.x < ki || (v.x == ki && (j + 0) < e));
        r += (v.y < ki || (v.y == ki && (j + 1) < e));
        r += (v.z < ki || (v.z == ki && (j + 2) < e));
        r += (v.w < ki || (v.w == ki && (j + 3) < e));
    }
    r += __shfl_down(r, 2, 4);
    r += __shfl_down(r, 1, 4);
    if (slice == 0) {
        keys[b * NN + r] = ki;
        sidx[b * NN + r] = e;
    }
}

// ---------------- K3a: per-chunk weighted sums, both weightings in one pass ----------------
// grid = B*NCH blocks, 128 threads.
__global__ __launch_bounds__(128)
void k3a_csum(const float* __restrict__ h, const float* __restrict__ keys,
              const int* __restrict__ sidx,
              float* __restrict__ csum1, float* __restrict__ csum2,
              float* __restrict__ ssum1, float* __restrict__ ssum2)
{
    const int bid = blockIdx.x;
    const int b = bid >> 5, c = bid & (NCH - 1);
    const int o = threadIdx.x;
    const int m0 = c * CH;

    __shared__ float lw1[CH], lw2[CH];
    __shared__ int li[CH];
    if (o < CH) {
        float kv = keys[b * NN + m0 + o];
        lw1[o] = expf(kv);
        lw2[o] = expf(LALPHA * kv);
        li[o] = sidx[b * NN + m0 + o];
    }
    __syncthreads();

    float a1 = 0.f, a2 = 0.f, s1 = 0.f, s2 = 0.f;
#pragma unroll 4
    for (int m = 0; m < CH; ++m) {
        float hv = h[(size_t)(b * NN + li[m]) * FF + o];
        float w1 = lw1[m], w2 = lw2[m];
        a1 += w1 * hv; a2 += w2 * hv;
        s1 += w1;      s2 += w2;
    }
    csum1[bid * FF + o] = a1;
    csum2[bid * FF + o] = a2;
    if (o == 0) { ssum1[bid] = s1; ssum2[bid] = s2; }
}

// ---------------- K4a: per-row partition point + counting-sort into chunk buckets ----------------
// grid = 64 blocks x 256 threads = 16384 rows.
__global__ __launch_bounds__(256)
void k4a_bucket(const float* __restrict__ si, const float* __restrict__ keys,
                int* __restrict__ parr, int* __restrict__ cnt, int* __restrict__ brows)
{
    const int gid = blockIdx.x * 256 + threadIdx.x;
    const int b = gid >> 11, i = gid & (NN - 1);
    const float thr = -si[b * NN + i];
    const float* kb = keys + b * NN;
    int lo = 0, hi = NN;
    while (lo < hi) {
        int mid = (lo + hi) >> 1;
        if (kb[mid] < thr) lo = mid + 1; else hi = mid;
    }
    parr[b * NN + i] = lo;
    int c = lo >> 6;
    if (c > NCH - 1) c = NCH - 1;
    int pos = atomicAdd(&cnt[b * NCH + c], 1);
    brows[(b * NCH + c) * NN + pos] = i;
}

// ---------------- K5: rebuild chunk prefixes in LDS + emit bucketed rows ----------------
// grid = B*NCH*2 blocks (feature halves), 64 threads.
__global__ __launch_bounds__(64)
void k5_emit(const float* __restrict__ h, const float* __restrict__ keys,
             const int* __restrict__ sidx, const float* __restrict__ si,
             const float* __restrict__ csum1, const float* __restrict__ csum2,
             const float* __restrict__ ssum1, const float* __restrict__ ssum2,
             const int* __restrict__ parr, const int* __restrict__ cnt,
             const int* __restrict__ brows, float* __restrict__ out)
{
    __shared__ float Pfx1[CH][64];   // exclusive prefix, weight e^k
    __shared__ float Pfx2[CH][64];   // exclusive prefix, weight e^{0.2k}
    __shared__ float lw1[CH], lw2[CH], sP1[CH], sP2[CH];
    __shared__ int li[CH];

    const int bid = blockIdx.x;
    const int half = bid & 1;
    const int c = (bid >> 1) & (NCH - 1);
    const int b = bid >> 6;
    const int o = threadIdx.x;           // 0..63
    const int m0 = c * CH;
    const int fo = half * 64 + o;        // feature index

    {
        float kv = keys[b * NN + m0 + o];
        lw1[o] = expf(kv);
        lw2[o] = expf(LALPHA * kv);
        li[o] = sidx[b * NN + m0 + o];
    }
    __syncthreads();

    // chunk-granular bases from csum/ssum
    float baseS1 = 0.f, baseP2 = 0.f, sb1 = 0.f, sb2 = 0.f;
    for (int c2 = c + 1; c2 < NCH; ++c2) {
        baseS1 += csum1[(b * NCH + c2) * FF + fo];
        sb1 += ssum1[b * NCH + c2];
    }
    for (int c2 = 0; c2 < c; ++c2) {
        baseP2 += csum2[(b * NCH + c2) * FF + fo];
        sb2 += ssum2[b * NCH + c2];
    }

    // in-chunk exclusive prefixes (all threads also track scalar prefixes redundantly)
    float a1 = 0.f, a2 = 0.f, s1 = 0.f, s2 = 0.f;
#pragma unroll 4
    for (int m = 0; m < CH; ++m) {
        Pfx1[m][o] = a1; Pfx2[m][o] = a2;
        if (o == 0) { sP1[m] = s1; sP2[m] = s2; }
        float hv = h[(size_t)(b * NN + li[m]) * FF + fo];
        float w1 = lw1[m], w2 = lw2[m];
        a1 += w1 * hv; a2 += w2 * hv;
        s1 += w1;      s2 += w2;
    }
    __syncthreads();

    const int nrows = cnt[b * NCH + c];
    const int* br = brows + (b * NCH + c) * NN;
    for (int r = 0; r < nrows; ++r) {
        int i = br[r];
        int rel = parr[b * NN + i] - m0;   // 0..CH (CH only possible at c==NCH-1)
        float siv = si[b * NN + i];
        float e1 = expf(siv), e2 = expf(LALPHA * siv);
        float p1, p2, t1, t2;
        if (rel < CH) { p1 = Pfx1[rel][o]; p2 = Pfx2[rel][o]; t1 = sP1[rel]; t2 = sP2[rel]; }
        else          { p1 = a1;           p2 = a2;           t1 = s1;       t2 = s2;       }
        float S1v = baseS1 + (a1 - p1);        // suffix incl. rel
        float P2v = baseP2 + p2;               // prefix excl. rel
        float den = e1 * (sb1 + (s1 - t1)) + e2 * (sb2 + t2);
        out[(size_t)(b * NN + i) * FF + fo] = (e1 * S1v + e2 * P2v) / den;
    }
}

extern "C" void kernel_launch(void* const* d_in, const int* in_sizes, int n_in,
                              void* d_out, int out_size, void* d_ws, size_t ws_size,
                              hipStream_t stream)
{
    const float* x = (const float*)d_in[0];
    const float* W = (const float*)d_in[1];
    const float* a = (const float*)d_in[2];
    float* out = (float*)d_out;

    float* ws = (float*)d_ws;
    float* h     = ws;                           // B*N*F
    float* si    = h + BB * NN * FF;             // B*N
    float* sj    = si + BB * NN;                 // B*N
    float* keys  = sj + BB * NN;                 // B*N
    int*   sidx  = (int*)(keys + BB * NN);       // B*N
    int*   parr  = sidx + BB * NN;               // B*N
    float* csum1 = (float*)(parr + BB * NN);     // B*NCH*F
    float* csum2 = csum1 + BB * NCH * FF;        // B*NCH*F
    float* ssum1 = csum2 + BB * NCH * FF;        // B*NCH
    float* ssum2 = ssum1 + BB * NCH;             // B*NCH
    int*   cnt   = (int*)(ssum2 + BB * NCH);     // B*NCH
    int*   brows = cnt + BB * NCH;               // B*NCH*NN

    hipLaunchKernelGGL(k1_h, dim3(BB * NN / 16), dim3(256), 0, stream, x, W, a, h, si, sj, cnt);
    hipLaunchKernelGGL(k2_rank, dim3(BB * 8), dim3(1024), 0, stream, sj, keys, sidx);
    hipLaunchKernelGGL(k3a_csum, dim3(BB * NCH), dim3(128), 0, stream, h, keys, sidx, csum1, csum2, ssum1, ssum2);
    hipLaunchKernelGGL(k4a_bucket, dim3(64), dim3(256), 0, stream, si, keys, parr, cnt, brows);
    hipLaunchKernelGGL(k5_emit, dim3(BB * NCH * 2), dim3(64), 0, stream, h, keys, sidx, si, csum1, csum2, ssum1, ssum2, parr, cnt, brows, out);
}

// Round 4
// 117.688 us; speedup vs baseline: 1.1105x; 1.1105x over previous
//
#include <hip/hip_runtime.h>
#include <math.h>

#define BB 8
#define NN 2048
#define FF 128
#define LALPHA 0.2f

#define CH 16
#define NCH (NN / CH)        // 128
#define NCP1 (NCH + 1)       // 129

#define WT_STRIDE 132   // 128 + 4 pad
#define XT_STRIDE 18    // 16 + 2 pad

// ---------------- K1: h = x @ W^T, si = h.a1, sj = h.a2 ----------------
__global__ __launch_bounds__(256, 2)
void k1_h(const float* __restrict__ x, const float* __restrict__ W,
          const float* __restrict__ a, float* __restrict__ h,
          float* __restrict__ si, float* __restrict__ sj)
{
    __shared__ float Wt[FF * WT_STRIDE];
    __shared__ float xsT[FF * XT_STRIDE];
    const int t = threadIdx.x;
    const int row0 = blockIdx.x * 16;

    for (int kk = t; kk < FF * FF; kk += 256) {
        int o = kk >> 7, f = kk & (FF - 1);
        Wt[f * WT_STRIDE + o] = W[kk];
    }
    for (int kk = t; kk < 16 * FF; kk += 256) {
        int r = kk >> 7, f = kk & (FF - 1);
        xsT[f * XT_STRIDE + r] = x[(row0 + r) * FF + f];
    }
    __syncthreads();

    const int oq = (t & 31) << 2;
    const int rp = t >> 5;
    float a00 = 0.f, a01 = 0.f, a02 = 0.f, a03 = 0.f;
    float a10 = 0.f, a11 = 0.f, a12 = 0.f, a13 = 0.f;
#pragma unroll 8
    for (int f = 0; f < FF; ++f) {
        float2 xv = *(const float2*)&xsT[f * XT_STRIDE + (rp << 1)];
        float4 wv = *(const float4*)&Wt[f * WT_STRIDE + oq];
        a00 += xv.x * wv.x; a01 += xv.x * wv.y; a02 += xv.x * wv.z; a03 += xv.x * wv.w;
        a10 += xv.y * wv.x; a11 += xv.y * wv.y; a12 += xv.y * wv.z; a13 += xv.y * wv.w;
    }
    const int r0 = row0 + (rp << 1), r1 = r0 + 1;
    *(float4*)&h[r0 * FF + oq] = make_float4(a00, a01, a02, a03);
    *(float4*)&h[r1 * FF + oq] = make_float4(a10, a11, a12, a13);

    const float4 a1v = *(const float4*)&a[oq];
    const float4 a2v = *(const float4*)&a[FF + oq];
    float s10 = a00 * a1v.x + a01 * a1v.y + a02 * a1v.z + a03 * a1v.w;
    float s11 = a10 * a1v.x + a11 * a1v.y + a12 * a1v.z + a13 * a1v.w;
    float s20 = a00 * a2v.x + a01 * a2v.y + a02 * a2v.z + a03 * a2v.w;
    float s21 = a10 * a2v.x + a11 * a2v.y + a12 * a2v.z + a13 * a2v.w;
#pragma unroll
    for (int off = 16; off >= 1; off >>= 1) {
        s10 += __shfl_down(s10, off, 32);
        s11 += __shfl_down(s11, off, 32);
        s20 += __shfl_down(s20, off, 32);
        s21 += __shfl_down(s21, off, 32);
    }
    if ((t & 31) == 0) {
        si[r0] = s10; si[r1] = s11;
        sj[r0] = s20; sj[r1] = s21;
    }
}

// ---------------- K2: rank-sort sj per batch ----------------
// grid = B*16 blocks, 1024 threads. Block = (batch, segment of 128 elems).
// Each element's rank computed by 8 threads; slices stride-interleaved so the
// 8 slices hit 8 distinct LDS banks (q = slice + 8*it).
__global__ __launch_bounds__(1024)
void k2_rank(const float* __restrict__ sj, float* __restrict__ keys, int* __restrict__ sidx)
{
    __shared__ float lk[NN];
    const int b = blockIdx.x >> 4;
    const int s = blockIdx.x & 15;
    const int t = threadIdx.x;
    for (int j = t; j < NN; j += 1024) lk[j] = sj[b * NN + j];
    __syncthreads();

    const int e = s * 128 + (t >> 3);   // element index in batch
    const int slice = t & 7;
    const float ki = lk[e];
    const float4* lk4 = (const float4*)lk;
    int r = 0;
#pragma unroll 8
    for (int it = 0; it < 64; ++it) {
        int q = slice + (it << 3);      // distinct bank per slice
        float4 v = lk4[q];
        int j = q << 2;
        r += (v.x < ki || (v.x == ki && (j + 0) < e));
        r += (v.y < ki || (v.y == ki && (j + 1) < e));
        r += (v.z < ki || (v.z == ki && (j + 2) < e));
        r += (v.w < ki || (v.w == ki && (j + 3) < e));
    }
    r += __shfl_down(r, 4, 8);
    r += __shfl_down(r, 2, 8);
    r += __shfl_down(r, 1, 8);
    if (slice == 0) {
        keys[b * NN + r] = ki;
        sidx[b * NN + r] = e;
    }
}

// ---------------- K3a: per-chunk weighted sums (both weights, one pass) ----------------
// grid = B*NCH = 1024 blocks, 128 threads (one per feature).
__global__ __launch_bounds__(128)
void k3a_csum(const float* __restrict__ h, const float* __restrict__ keys,
              const int* __restrict__ sidx,
              float* __restrict__ csum1, float* __restrict__ csum2,
              float* __restrict__ ssum1, float* __restrict__ ssum2)
{
    const int bid = blockIdx.x;
    const int b = bid >> 7, c = bid & (NCH - 1);
    const int o = threadIdx.x;
    const int m0 = c * CH;

    __shared__ float lw1[CH], lw2[CH];
    __shared__ int li[CH];
    if (o < CH) {
        float kv = keys[b * NN + m0 + o];
        lw1[o] = expf(kv);
        lw2[o] = expf(LALPHA * kv);
        li[o] = sidx[b * NN + m0 + o];
    }
    __syncthreads();

    float a1 = 0.f, a2 = 0.f, s1 = 0.f, s2 = 0.f;
#pragma unroll
    for (int m = 0; m < CH; ++m) {
        float hv = h[(size_t)(b * NN + li[m]) * FF + o];
        float w1 = lw1[m], w2 = lw2[m];
        a1 += w1 * hv; a2 += w2 * hv;
        s1 += w1;      s2 += w2;
    }
    csum1[bid * FF + o] = a1;
    csum2[bid * FF + o] = a2;
    if (o == 0) { ssum1[bid] = s1; ssum2[bid] = s2; }
}

// ---------------- K3s: chunk-granular scanned sums (redundant per-block sum) ----------------
// grid = B*NCP1 blocks, 128 threads. Block (b,c):
//   CS1[c] = sum_{c2>=c} csum1[c2]   (+ TS1 scalar)
//   CP2[c] = sum_{c2<c}  csum2[c2]   (+ TP2 scalar)
// The two loops together touch exactly NCH rows — uniform cost per block.
__global__ __launch_bounds__(128)
void k3s_scan(const float* __restrict__ csum1, const float* __restrict__ csum2,
              const float* __restrict__ ssum1, const float* __restrict__ ssum2,
              float* __restrict__ CS1, float* __restrict__ CP2,
              float* __restrict__ TS1, float* __restrict__ TP2)
{
    const int bid = blockIdx.x;
    const int b = bid / NCP1;
    const int c = bid - b * NCP1;
    const int o = threadIdx.x;

    float a1 = 0.f, s1 = 0.f;
    for (int c2 = c; c2 < NCH; ++c2) {
        a1 += csum1[(size_t)(b * NCH + c2) * FF + o];
        s1 += ssum1[b * NCH + c2];
    }
    float a2 = 0.f, s2 = 0.f;
    for (int c2 = 0; c2 < c; ++c2) {
        a2 += csum2[(size_t)(b * NCH + c2) * FF + o];
        s2 += ssum2[b * NCH + c2];
    }
    CS1[(size_t)bid * FF + o] = a1;
    CP2[(size_t)bid * FF + o] = a2;
    if (o == 0) { TS1[bid] = s1; TP2[bid] = s2; }
}

// ---------------- K4: per-row output ----------------
// grid = B*N = 16384 blocks, 128 threads. Redundant binary search (uniform,
// cached), then 16-iteration predicated in-chunk gather + blend.
__global__ __launch_bounds__(128)
void k4_out(const float* __restrict__ h, const float* __restrict__ keys,
            const int* __restrict__ sidx, const float* __restrict__ si,
            const float* __restrict__ CS1, const float* __restrict__ CP2,
            const float* __restrict__ TS1, const float* __restrict__ TP2,
            float* __restrict__ out)
{
    const int bi = blockIdx.x;
    const int b = bi >> 11, i = bi & (NN - 1);
    const int o = threadIdx.x;
    const float siv = si[b * NN + i];
    const float thr = -siv;
    const float* kb = keys + b * NN;

    int lo = 0, hi = NN;
    while (lo < hi) {                  // lower_bound: first m with key[m] >= -si
        int mid = (lo + hi) >> 1;
        if (kb[mid] < thr) lo = mid + 1; else hi = mid;
    }
    const int p = lo;
    int c = p >> 4; if (c > NCH - 1) c = NCH - 1;
    const int rel = p - (c << 4);      // 0..16 (16 only when p==NN)

    __shared__ float lw1[CH], lw2[CH];
    __shared__ int li[CH];
    if (o < CH) {
        float kv = kb[(c << 4) + o];
        lw1[o] = expf(kv);
        lw2[o] = expf(LALPHA * kv);
        li[o] = sidx[b * NN + (c << 4) + o];
    }
    __syncthreads();

    float a1 = 0.f, a2 = 0.f, s1 = 0.f, s2 = 0.f;
#pragma unroll
    for (int m = 0; m < CH; ++m) {     // condition uniform across block: no divergence
        float hv = h[(size_t)(b * NN + li[m]) * FF + o];
        float w1 = lw1[m], w2 = lw2[m];
        if (m >= rel) { a1 += w1 * hv; s1 += w1; }
        else          { a2 += w2 * hv; s2 += w2; }
    }

    const size_t sbase = (size_t)(b * NCP1 + c + 1) * FF;   // suffix from chunk c+1
    const size_t pbase = (size_t)(b * NCP1 + c) * FF;       // prefix of chunks < c
    const float S1v = CS1[sbase + o] + a1;
    const float P2v = CP2[pbase + o] + a2;
    const float e1 = expf(siv), e2 = expf(LALPHA * siv);
    const float den = e1 * (TS1[b * NCP1 + c + 1] + s1) + e2 * (TP2[b * NCP1 + c] + s2);
    out[(size_t)(b * NN + i) * FF + o] = (e1 * S1v + e2 * P2v) / den;
}

extern "C" void kernel_launch(void* const* d_in, const int* in_sizes, int n_in,
                              void* d_out, int out_size, void* d_ws, size_t ws_size,
                              hipStream_t stream)
{
    const float* x = (const float*)d_in[0];
    const float* W = (const float*)d_in[1];
    const float* a = (const float*)d_in[2];
    float* out = (float*)d_out;

    float* ws = (float*)d_ws;
    float* h     = ws;                           // B*N*F          = 2M
    float* si    = h + BB * NN * FF;             // B*N
    float* sj    = si + BB * NN;                 // B*N
    float* keys  = sj + BB * NN;                 // B*N
    int*   sidx  = (int*)(keys + BB * NN);       // B*N
    float* csum1 = (float*)(sidx + BB * NN);     // B*NCH*F
    float* csum2 = csum1 + BB * NCH * FF;        // B*NCH*F
    float* ssum1 = csum2 + BB * NCH * FF;        // B*NCH
    float* ssum2 = ssum1 + BB * NCH;             // B*NCH
    float* CS1   = ssum2 + BB * NCH;             // B*NCP1*F
    float* CP2   = CS1 + BB * NCP1 * FF;         // B*NCP1*F
    float* TS1   = CP2 + BB * NCP1 * FF;         // B*NCP1
    float* TP2   = TS1 + BB * NCP1;              // B*NCP1

    hipLaunchKernelGGL(k1_h, dim3(BB * NN / 16), dim3(256), 0, stream, x, W, a, h, si, sj);
    hipLaunchKernelGGL(k2_rank, dim3(BB * 16), dim3(1024), 0, stream, sj, keys, sidx);
    hipLaunchKernelGGL(k3a_csum, dim3(BB * NCH), dim3(128), 0, stream, h, keys, sidx, csum1, csum2, ssum1, ssum2);
    hipLaunchKernelGGL(k3s_scan, dim3(BB * NCP1), dim3(128), 0, stream, csum1, csum2, ssum1, ssum2, CS1, CP2, TS1, TP2);
    hipLaunchKernelGGL(k4_out, dim3(BB * NN), dim3(128), 0, stream, h, keys, sidx, si, CS1, CP2, TS1, TP2, out);
}

// Round 5
// 94.796 us; speedup vs baseline: 1.3787x; 1.2415x over previous
//
#include <hip/hip_runtime.h>
#include <math.h>

#define BB 8
#define NN 2048
#define FF 128
#define NP1 (NN + 1)
#define LALPHA 0.2f

#define CH 16
#define NCH (NN / CH)        // 128
#define NCP1 (NCH + 1)       // 129

#define WT_STRIDE 132   // 128 + 4 pad
#define XT_STRIDE 18    // 16 + 2 pad

// ---------------- K1: h = x @ W^T, si = h.a1, sj = h.a2 ----------------
__global__ __launch_bounds__(256, 2)
void k1_h(const float* __restrict__ x, const float* __restrict__ W,
          const float* __restrict__ a, float* __restrict__ h,
          float* __restrict__ si, float* __restrict__ sj)
{
    __shared__ float Wt[FF * WT_STRIDE];
    __shared__ float xsT[FF * XT_STRIDE];
    const int t = threadIdx.x;
    const int row0 = blockIdx.x * 16;

    for (int kk = t; kk < FF * FF; kk += 256) {
        int o = kk >> 7, f = kk & (FF - 1);
        Wt[f * WT_STRIDE + o] = W[kk];
    }
    for (int kk = t; kk < 16 * FF; kk += 256) {
        int r = kk >> 7, f = kk & (FF - 1);
        xsT[f * XT_STRIDE + r] = x[(row0 + r) * FF + f];
    }
    __syncthreads();

    const int oq = (t & 31) << 2;
    const int rp = t >> 5;
    float a00 = 0.f, a01 = 0.f, a02 = 0.f, a03 = 0.f;
    float a10 = 0.f, a11 = 0.f, a12 = 0.f, a13 = 0.f;
#pragma unroll 8
    for (int f = 0; f < FF; ++f) {
        float2 xv = *(const float2*)&xsT[f * XT_STRIDE + (rp << 1)];
        float4 wv = *(const float4*)&Wt[f * WT_STRIDE + oq];
        a00 += xv.x * wv.x; a01 += xv.x * wv.y; a02 += xv.x * wv.z; a03 += xv.x * wv.w;
        a10 += xv.y * wv.x; a11 += xv.y * wv.y; a12 += xv.y * wv.z; a13 += xv.y * wv.w;
    }
    const int r0 = row0 + (rp << 1), r1 = r0 + 1;
    *(float4*)&h[r0 * FF + oq] = make_float4(a00, a01, a02, a03);
    *(float4*)&h[r1 * FF + oq] = make_float4(a10, a11, a12, a13);

    const float4 a1v = *(const float4*)&a[oq];
    const float4 a2v = *(const float4*)&a[FF + oq];
    float s10 = a00 * a1v.x + a01 * a1v.y + a02 * a1v.z + a03 * a1v.w;
    float s11 = a10 * a1v.x + a11 * a1v.y + a12 * a1v.z + a13 * a1v.w;
    float s20 = a00 * a2v.x + a01 * a2v.y + a02 * a2v.z + a03 * a2v.w;
    float s21 = a10 * a2v.x + a11 * a2v.y + a12 * a2v.z + a13 * a2v.w;
#pragma unroll
    for (int off = 16; off >= 1; off >>= 1) {
        s10 += __shfl_down(s10, off, 32);
        s11 += __shfl_down(s11, off, 32);
        s20 += __shfl_down(s20, off, 32);
        s21 += __shfl_down(s21, off, 32);
    }
    if ((t & 31) == 0) {
        si[r0] = s10; si[r1] = s11;
        sj[r0] = s20; sj[r1] = s21;
    }
}

// ---------------- K2: rank-sort sj per batch ----------------
__global__ __launch_bounds__(1024)
void k2_rank(const float* __restrict__ sj, float* __restrict__ keys, int* __restrict__ sidx)
{
    __shared__ float lk[NN];
    const int b = blockIdx.x >> 4;
    const int s = blockIdx.x & 15;
    const int t = threadIdx.x;
    for (int j = t; j < NN; j += 1024) lk[j] = sj[b * NN + j];
    __syncthreads();

    const int e = s * 128 + (t >> 3);
    const int slice = t & 7;
    const float ki = lk[e];
    const float4* lk4 = (const float4*)lk;
    int r = 0;
#pragma unroll 8
    for (int it = 0; it < 64; ++it) {
        int q = slice + (it << 3);
        float4 v = lk4[q];
        int j = q << 2;
        r += (v.x < ki || (v.x == ki && (j + 0) < e));
        r += (v.y < ki || (v.y == ki && (j + 1) < e));
        r += (v.z < ki || (v.z == ki && (j + 2) < e));
        r += (v.w < ki || (v.w == ki && (j + 3) < e));
    }
    r += __shfl_down(r, 4, 8);
    r += __shfl_down(r, 2, 8);
    r += __shfl_down(r, 1, 8);
    if (slice == 0) {
        keys[b * NN + r] = ki;
        sidx[b * NN + r] = e;
    }
}

// ---------------- K2b: per-row partition point via LDS-staged binary search ----------------
// grid = 64 blocks x 256 threads; block covers 256 consecutive rows of one batch.
__global__ __launch_bounds__(256)
void k2b_search(const float* __restrict__ keys, const float* __restrict__ si,
                int* __restrict__ parr)
{
    __shared__ float lk[NN];
    const int b = blockIdx.x >> 3;
    const int t = threadIdx.x;
    for (int j = t; j < NN; j += 256) lk[j] = keys[b * NN + j];
    __syncthreads();

    const int i = ((blockIdx.x & 7) << 8) + t;
    const float thr = -si[b * NN + i];
    int lo = 0, hi = NN;
    while (lo < hi) {                 // lower_bound: first m with key[m] >= -si
        int mid = (lo + hi) >> 1;
        if (lk[mid] < thr) lo = mid + 1; else hi = mid;
    }
    parr[b * NN + i] = lo;
}

// ---------------- K3a: per-chunk weighted sums (both weights), prefetch-then-sum ----------------
// grid = B*NCH = 1024 blocks, 128 threads.
__global__ __launch_bounds__(128)
void k3a_csum(const float* __restrict__ h, const float* __restrict__ keys,
              const int* __restrict__ sidx,
              float* __restrict__ csum1, float* __restrict__ csum2,
              float* __restrict__ ssum1, float* __restrict__ ssum2)
{
    const int bid = blockIdx.x;
    const int b = bid >> 7, c = bid & (NCH - 1);
    const int o = threadIdx.x;
    const int m0 = c * CH;

    __shared__ float lw1[CH], lw2[CH];
    __shared__ int li[CH];
    if (o < CH) {
        float kv = keys[b * NN + m0 + o];
        lw1[o] = expf(kv);
        lw2[o] = expf(LALPHA * kv);
        li[o] = sidx[b * NN + m0 + o];
    }
    __syncthreads();

    float r[CH];
#pragma unroll
    for (int m = 0; m < CH; ++m)
        r[m] = h[(size_t)(b * NN + li[m]) * FF + o];

    float a1 = 0.f, a2 = 0.f, s1 = 0.f, s2 = 0.f;
#pragma unroll
    for (int m = 0; m < CH; ++m) {
        float w1 = lw1[m], w2 = lw2[m];
        a1 += w1 * r[m]; a2 += w2 * r[m];
        s1 += w1;        s2 += w2;
    }
    csum1[(size_t)bid * FF + o] = a1;
    csum2[(size_t)bid * FF + o] = a2;
    if (o == 0) { ssum1[bid] = s1; ssum2[bid] = s2; }
}

// ---------------- K3s: chunk-granular scanned sums ----------------
// grid = B*NCP1 = 1032 blocks, 128 threads.
__global__ __launch_bounds__(128)
void k3s_scan(const float* __restrict__ csum1, const float* __restrict__ csum2,
              const float* __restrict__ ssum1, const float* __restrict__ ssum2,
              float* __restrict__ CS1, float* __restrict__ CP2,
              float* __restrict__ TS1, float* __restrict__ TP2)
{
    const int bid = blockIdx.x;
    const int b = bid / NCP1;
    const int c = bid - b * NCP1;
    const int o = threadIdx.x;

    float a1 = 0.f, s1 = 0.f;
    for (int c2 = c; c2 < NCH; ++c2) {
        a1 += csum1[(size_t)(b * NCH + c2) * FF + o];
        s1 += ssum1[b * NCH + c2];
    }
    float a2 = 0.f, s2 = 0.f;
    for (int c2 = 0; c2 < c; ++c2) {
        a2 += csum2[(size_t)(b * NCH + c2) * FF + o];
        s2 += ssum2[b * NCH + c2];
    }
    CS1[(size_t)bid * FF + o] = a1;
    CP2[(size_t)bid * FF + o] = a2;
    if (o == 0) { TS1[bid] = s1; TP2[bid] = s2; }
}

// ---------------- K3p: materialize per-position prefix/suffix rows ----------------
// grid = B*NCH = 1024 blocks, 128 threads. Prefetch 16 rows into registers,
// then two register scans with coalesced stores.
__global__ __launch_bounds__(128)
void k3p_fill(const float* __restrict__ h, const float* __restrict__ keys,
              const int* __restrict__ sidx,
              const float* __restrict__ CS1, const float* __restrict__ CP2,
              const float* __restrict__ TS1, const float* __restrict__ TP2,
              float* __restrict__ S1, float* __restrict__ P2,
              float* __restrict__ T1, float* __restrict__ T2)
{
    const int bid = blockIdx.x;
    const int b = bid >> 7, c = bid & (NCH - 1);
    const int o = threadIdx.x;
    const int m0 = c * CH;

    __shared__ float lw1[CH], lw2[CH];
    __shared__ int li[CH];
    if (o < CH) {
        float kv = keys[b * NN + m0 + o];
        lw1[o] = expf(kv);
        lw2[o] = expf(LALPHA * kv);
        li[o] = sidx[b * NN + m0 + o];
    }
    __syncthreads();

    float r[CH];
#pragma unroll
    for (int m = 0; m < CH; ++m)
        r[m] = h[(size_t)(b * NN + li[m]) * FF + o];

    const float baseS1 = CS1[(size_t)(b * NCP1 + c + 1) * FF + o];
    const float baseP2 = CP2[(size_t)(b * NCP1 + c) * FF + o];
    const float tS1 = TS1[b * NCP1 + c + 1];
    const float tP2 = TP2[b * NCP1 + c];

    // inclusive suffix with weight e^{key}
    float acc = baseS1, sacc = tS1;
#pragma unroll
    for (int m = CH - 1; m >= 0; --m) {
        acc += lw1[m] * r[m]; sacc += lw1[m];
        S1[(size_t)(b * NP1 + m0 + m) * FF + o] = acc;
        if (o == 0) T1[b * NP1 + m0 + m] = sacc;
    }
    // exclusive prefix with weight e^{0.2 key}
    float acc2 = baseP2, sacc2 = tP2;
#pragma unroll
    for (int m = 0; m < CH; ++m) {
        P2[(size_t)(b * NP1 + m0 + m) * FF + o] = acc2;
        if (o == 0) T2[b * NP1 + m0 + m] = sacc2;
        acc2 += lw2[m] * r[m]; sacc2 += lw2[m];
    }
    if (c == NCH - 1) {
        S1[(size_t)(b * NP1 + NN) * FF + o] = 0.f;
        P2[(size_t)(b * NP1 + NN) * FF + o] = acc2;
        if (o == 0) { T1[b * NP1 + NN] = 0.f; T2[b * NP1 + NN] = sacc2; }
    }
}

// ---------------- K4: per-row blend ----------------
// grid = B*N = 16384 blocks, 128 threads.
__global__ __launch_bounds__(128)
void k4_out(const float* __restrict__ si, const int* __restrict__ parr,
            const float* __restrict__ S1, const float* __restrict__ P2,
            const float* __restrict__ T1, const float* __restrict__ T2,
            float* __restrict__ out)
{
    const int bi = blockIdx.x;
    const int b = bi >> 11, i = bi & (NN - 1);
    const int o = threadIdx.x;
    const int p = parr[b * NN + i];
    const float siv = si[b * NN + i];
    const float e1 = expf(siv), e2 = expf(LALPHA * siv);
    const float num = e1 * S1[(size_t)(b * NP1 + p) * FF + o]
                    + e2 * P2[(size_t)(b * NP1 + p) * FF + o];
    const float den = e1 * T1[b * NP1 + p] + e2 * T2[b * NP1 + p];
    out[(size_t)(b * NN + i) * FF + o] = num / den;
}

extern "C" void kernel_launch(void* const* d_in, const int* in_sizes, int n_in,
                              void* d_out, int out_size, void* d_ws, size_t ws_size,
                              hipStream_t stream)
{
    const float* x = (const float*)d_in[0];
    const float* W = (const float*)d_in[1];
    const float* a = (const float*)d_in[2];
    float* out = (float*)d_out;

    float* ws = (float*)d_ws;
    float* h     = ws;                           // B*N*F
    float* si    = h + BB * NN * FF;             // B*N
    float* sj    = si + BB * NN;                 // B*N
    float* keys  = sj + BB * NN;                 // B*N
    int*   sidx  = (int*)(keys + BB * NN);       // B*N
    int*   parr  = sidx + BB * NN;               // B*N
    float* csum1 = (float*)(parr + BB * NN);     // B*NCH*F
    float* csum2 = csum1 + BB * NCH * FF;        // B*NCH*F
    float* ssum1 = csum2 + BB * NCH * FF;        // B*NCH
    float* ssum2 = ssum1 + BB * NCH;             // B*NCH
    float* CS1   = ssum2 + BB * NCH;             // B*NCP1*F
    float* CP2   = CS1 + BB * NCP1 * FF;         // B*NCP1*F
    float* TS1   = CP2 + BB * NCP1 * FF;         // B*NCP1
    float* TP2   = TS1 + BB * NCP1;              // B*NCP1
    float* S1    = TP2 + BB * NCP1;              // B*NP1*F
    float* P2    = S1 + BB * NP1 * FF;           // B*NP1*F
    float* T1    = P2 + BB * NP1 * FF;           // B*NP1
    float* T2    = T1 + BB * NP1;                // B*NP1

    hipLaunchKernelGGL(k1_h, dim3(BB * NN / 16), dim3(256), 0, stream, x, W, a, h, si, sj);
    hipLaunchKernelGGL(k2_rank, dim3(BB * 16), dim3(1024), 0, stream, sj, keys, sidx);
    hipLaunchKernelGGL(k2b_search, dim3(64), dim3(256), 0, stream, keys, si, parr);
    hipLaunchKernelGGL(k3a_csum, dim3(BB * NCH), dim3(128), 0, stream, h, keys, sidx, csum1, csum2, ssum1, ssum2);
    hipLaunchKernelGGL(k3s_scan, dim3(BB * NCP1), dim3(128), 0, stream, csum1, csum2, ssum1, ssum2, CS1, CP2, TS1, TP2);
    hipLaunchKernelGGL(k3p_fill, dim3(BB * NCH), dim3(128), 0, stream, h, keys, sidx, CS1, CP2, TS1, TP2, S1, P2, T1, T2);
    hipLaunchKernelGGL(k4_out, dim3(BB * NN), dim3(128), 0, stream, si, parr, S1, P2, T1, T2, out);
}

// Round 6
// 69.722 us; speedup vs baseline: 1.8745x; 1.3596x over previous
//
#include <hip/hip_runtime.h>
#include <math.h>

#define BB 8
#define NN 2048
#define FF 128
#define NP1 (NN + 1)
#define LALPHA 0.2f

#define CH 16
#define NCH (NN / CH)        // 128

// ---------------- K1: h = x @ W^T, si = h.a1, sj = h.a2 ----------------
// 256 blocks (1/CU) x 256 threads; 64 rows x 128 cols per block;
// thread tile = 4 rows x 8 cols -> 32 FMAs per 3 LDS b128 reads.
#define K1R 64
__global__ __launch_bounds__(256, 1)
void k1_h(const float* __restrict__ x, const float* __restrict__ W,
          const float* __restrict__ a, float* __restrict__ h,
          float* __restrict__ si, float* __restrict__ sj)
{
    __shared__ float Wt[FF * 132];    // Wt[f*132 + o] = W[o][f]   (67.6 KB)
    __shared__ float Xt[FF * 68];     // Xt[f*68 + r] = x[row0+r][f] (34.8 KB)
    const int t = threadIdx.x;
    const int row0 = blockIdx.x * K1R;

    for (int kk = t; kk < FF * FF; kk += 256) {
        int o = kk >> 7, f = kk & (FF - 1);
        Wt[f * 132 + o] = W[kk];
    }
    for (int kk = t; kk < K1R * FF; kk += 256) {
        int r = kk >> 7, f = kk & (FF - 1);
        Xt[f * 68 + r] = x[(row0 + r) * FF + f];
    }
    __syncthreads();

    const int tx = t & 15, ty = t >> 4;
    const int oq = tx << 3;           // 8 cols
    const int rq = ty << 2;           // 4 rows
    float acc[4][8];
#pragma unroll
    for (int r = 0; r < 4; ++r)
#pragma unroll
        for (int c = 0; c < 8; ++c) acc[r][c] = 0.f;

#pragma unroll 4
    for (int f = 0; f < FF; ++f) {
        float4 xv = *(const float4*)&Xt[f * 68 + rq];
        float4 w0 = *(const float4*)&Wt[f * 132 + oq];
        float4 w1 = *(const float4*)&Wt[f * 132 + oq + 4];
        const float xr[4] = {xv.x, xv.y, xv.z, xv.w};
        const float wc[8] = {w0.x, w0.y, w0.z, w0.w, w1.x, w1.y, w1.z, w1.w};
#pragma unroll
        for (int r = 0; r < 4; ++r)
#pragma unroll
            for (int c = 0; c < 8; ++c)
                acc[r][c] += xr[r] * wc[c];
    }

    // store h (coalesced float4 x2 per row)
#pragma unroll
    for (int r = 0; r < 4; ++r) {
        float* hp = &h[(size_t)(row0 + rq + r) * FF + oq];
        *(float4*)hp       = make_float4(acc[r][0], acc[r][1], acc[r][2], acc[r][3]);
        *(float4*)(hp + 4) = make_float4(acc[r][4], acc[r][5], acc[r][6], acc[r][7]);
    }

    // si/sj: per-thread partial over 8 cols, reduce across 16 tx lanes
    const float4 a10 = *(const float4*)&a[oq];
    const float4 a11 = *(const float4*)&a[oq + 4];
    const float4 a20 = *(const float4*)&a[FF + oq];
    const float4 a21 = *(const float4*)&a[FF + oq + 4];
    const float a1v[8] = {a10.x, a10.y, a10.z, a10.w, a11.x, a11.y, a11.z, a11.w};
    const float a2v[8] = {a20.x, a20.y, a20.z, a20.w, a21.x, a21.y, a21.z, a21.w};
#pragma unroll
    for (int r = 0; r < 4; ++r) {
        float s1 = 0.f, s2 = 0.f;
#pragma unroll
        for (int c = 0; c < 8; ++c) { s1 += acc[r][c] * a1v[c]; s2 += acc[r][c] * a2v[c]; }
#pragma unroll
        for (int off = 8; off >= 1; off >>= 1) {
            s1 += __shfl_down(s1, off, 16);
            s2 += __shfl_down(s2, off, 16);
        }
        if (tx == 0) {
            si[row0 + rq + r] = s1;
            sj[row0 + rq + r] = s2;
        }
    }
}

// ---------------- K2: rank-sort sj per batch ----------------
__global__ __launch_bounds__(1024)
void k2_rank(const float* __restrict__ sj, float* __restrict__ keys, int* __restrict__ sidx)
{
    __shared__ float lk[NN];
    const int b = blockIdx.x >> 4;
    const int s = blockIdx.x & 15;
    const int t = threadIdx.x;
    for (int j = t; j < NN; j += 1024) lk[j] = sj[b * NN + j];
    __syncthreads();

    const int e = s * 128 + (t >> 3);
    const int slice = t & 7;
    const float ki = lk[e];
    const float4* lk4 = (const float4*)lk;
    int r = 0;
#pragma unroll 8
    for (int it = 0; it < 64; ++it) {
        int q = slice + (it << 3);
        float4 v = lk4[q];
        int j = q << 2;
        r += (v.x < ki || (v.x == ki && (j + 0) < e));
        r += (v.y < ki || (v.y == ki && (j + 1) < e));
        r += (v.z < ki || (v.z == ki && (j + 2) < e));
        r += (v.w < ki || (v.w == ki && (j + 3) < e));
    }
    r += __shfl_down(r, 4, 8);
    r += __shfl_down(r, 2, 8);
    r += __shfl_down(r, 1, 8);
    if (slice == 0) {
        keys[b * NN + r] = ki;
        sidx[b * NN + r] = e;
    }
}

// ---------------- K3a: per-chunk weighted sums (both weights) ----------------
// grid = B*NCH = 1024 blocks, 128 threads.
__global__ __launch_bounds__(128)
void k3a_csum(const float* __restrict__ h, const float* __restrict__ keys,
              const int* __restrict__ sidx,
              float* __restrict__ csum1, float* __restrict__ csum2,
              float* __restrict__ ssum1, float* __restrict__ ssum2)
{
    const int bid = blockIdx.x;
    const int b = bid >> 7, c = bid & (NCH - 1);
    const int o = threadIdx.x;
    const int m0 = c * CH;

    __shared__ float lw1[CH], lw2[CH];
    __shared__ int li[CH];
    if (o < CH) {
        float kv = keys[b * NN + m0 + o];
        lw1[o] = expf(kv);
        lw2[o] = expf(LALPHA * kv);
        li[o] = sidx[b * NN + m0 + o];
    }
    __syncthreads();

    float r[CH];
#pragma unroll
    for (int m = 0; m < CH; ++m)
        r[m] = h[(size_t)(b * NN + li[m]) * FF + o];

    float a1 = 0.f, a2 = 0.f, s1 = 0.f, s2 = 0.f;
#pragma unroll
    for (int m = 0; m < CH; ++m) {
        float w1 = lw1[m], w2 = lw2[m];
        a1 += w1 * r[m]; a2 += w2 * r[m];
        s1 += w1;        s2 += w2;
    }
    csum1[(size_t)bid * FF + o] = a1;
    csum2[(size_t)bid * FF + o] = a2;
    if (o == 0) { ssum1[bid] = s1; ssum2[bid] = s2; }
}

// ---------------- K3sp: fused scan + per-position fill ----------------
// grid = B*NCH = 1024 blocks, 128 threads. Each block computes its own chunk
// bases (127 streamed csum rows), then scans its 16 positions and writes
// S1/P2/T1/T2 rows.
__global__ __launch_bounds__(128)
void k3sp_fill(const float* __restrict__ h, const float* __restrict__ keys,
               const int* __restrict__ sidx,
               const float* __restrict__ csum1, const float* __restrict__ csum2,
               const float* __restrict__ ssum1, const float* __restrict__ ssum2,
               float* __restrict__ S1, float* __restrict__ P2,
               float* __restrict__ T1, float* __restrict__ T2)
{
    const int bid = blockIdx.x;
    const int b = bid >> 7, c = bid & (NCH - 1);
    const int o = threadIdx.x;
    const int m0 = c * CH;

    __shared__ float lw1[CH], lw2[CH];
    __shared__ int li[CH];
    if (o < CH) {
        float kv = keys[b * NN + m0 + o];
        lw1[o] = expf(kv);
        lw2[o] = expf(LALPHA * kv);
        li[o] = sidx[b * NN + m0 + o];
    }
    __syncthreads();

    // issue gathers first; latency hides under the base loops
    float r[CH];
#pragma unroll
    for (int m = 0; m < CH; ++m)
        r[m] = h[(size_t)(b * NN + li[m]) * FF + o];

    float bS1 = 0.f, tS1 = 0.f;
#pragma unroll 4
    for (int c2 = c + 1; c2 < NCH; ++c2) {
        bS1 += csum1[(size_t)(b * NCH + c2) * FF + o];
        tS1 += ssum1[b * NCH + c2];
    }
    float bP2 = 0.f, tP2 = 0.f;
#pragma unroll 4
    for (int c2 = 0; c2 < c; ++c2) {
        bP2 += csum2[(size_t)(b * NCH + c2) * FF + o];
        tP2 += ssum2[b * NCH + c2];
    }

    // inclusive suffix, weight e^{key}
    float acc = bS1, sacc = tS1;
#pragma unroll
    for (int m = CH - 1; m >= 0; --m) {
        acc += lw1[m] * r[m]; sacc += lw1[m];
        S1[(size_t)(b * NP1 + m0 + m) * FF + o] = acc;
        if (o == 0) T1[b * NP1 + m0 + m] = sacc;
    }
    // exclusive prefix, weight e^{0.2 key}
    float acc2 = bP2, sacc2 = tP2;
#pragma unroll
    for (int m = 0; m < CH; ++m) {
        P2[(size_t)(b * NP1 + m0 + m) * FF + o] = acc2;
        if (o == 0) T2[b * NP1 + m0 + m] = sacc2;
        acc2 += lw2[m] * r[m]; sacc2 += lw2[m];
    }
    if (c == NCH - 1) {
        S1[(size_t)(b * NP1 + NN) * FF + o] = 0.f;
        P2[(size_t)(b * NP1 + NN) * FF + o] = acc2;
        if (o == 0) { T1[b * NP1 + NN] = 0.f; T2[b * NP1 + NN] = sacc2; }
    }
}

// ---------------- K4: per-row inline search + blend ----------------
// grid = B*N = 16384 blocks, 128 threads.
__global__ __launch_bounds__(128)
void k4_out(const float* __restrict__ si, const float* __restrict__ keys,
            const float* __restrict__ S1, const float* __restrict__ P2,
            const float* __restrict__ T1, const float* __restrict__ T2,
            float* __restrict__ out)
{
    const int bi = blockIdx.x;
    const int b = bi >> 11, i = bi & (NN - 1);
    const int o = threadIdx.x;
    const float siv = si[b * NN + i];
    const float thr = -siv;
    const float* kb = keys + b * NN;
    int lo = 0, hi = NN;
    while (lo < hi) {                 // lower_bound: first m with key[m] >= -si
        int mid = (lo + hi) >> 1;
        if (kb[mid] < thr) lo = mid + 1; else hi = mid;
    }
    const int p = lo;
    const float e1 = expf(siv), e2 = expf(LALPHA * siv);
    const float num = e1 * S1[(size_t)(b * NP1 + p) * FF + o]
                    + e2 * P2[(size_t)(b * NP1 + p) * FF + o];
    const float den = e1 * T1[b * NP1 + p] + e2 * T2[b * NP1 + p];
    out[(size_t)(b * NN + i) * FF + o] = num / den;
}

extern "C" void kernel_launch(void* const* d_in, const int* in_sizes, int n_in,
                              void* d_out, int out_size, void* d_ws, size_t ws_size,
                              hipStream_t stream)
{
    const float* x = (const float*)d_in[0];
    const float* W = (const float*)d_in[1];
    const float* a = (const float*)d_in[2];
    float* out = (float*)d_out;

    float* ws = (float*)d_ws;
    float* h     = ws;                           // B*N*F
    float* si    = h + BB * NN * FF;             // B*N
    float* sj    = si + BB * NN;                 // B*N
    float* keys  = sj + BB * NN;                 // B*N
    int*   sidx  = (int*)(keys + BB * NN);       // B*N
    float* csum1 = (float*)(sidx + BB * NN);     // B*NCH*F
    float* csum2 = csum1 + BB * NCH * FF;        // B*NCH*F
    float* ssum1 = csum2 + BB * NCH * FF;        // B*NCH
    float* ssum2 = ssum1 + BB * NCH;             // B*NCH
    float* S1    = ssum2 + BB * NCH;             // B*NP1*F
    float* P2    = S1 + BB * NP1 * FF;           // B*NP1*F
    float* T1    = P2 + BB * NP1 * FF;           // B*NP1
    float* T2    = T1 + BB * NP1;                // B*NP1

    hipLaunchKernelGGL(k1_h, dim3(BB * NN / K1R), dim3(256), 0, stream, x, W, a, h, si, sj);
    hipLaunchKernelGGL(k2_rank, dim3(BB * 16), dim3(1024), 0, stream, sj, keys, sidx);
    hipLaunchKernelGGL(k3a_csum, dim3(BB * NCH), dim3(128), 0, stream, h, keys, sidx, csum1, csum2, ssum1, ssum2);
    hipLaunchKernelGGL(k3sp_fill, dim3(BB * NCH), dim3(128), 0, stream, h, keys, sidx, csum1, csum2, ssum1, ssum2, S1, P2, T1, T2);
    hipLaunchKernelGGL(k4_out, dim3(BB * NN), dim3(128), 0, stream, si, keys, S1, P2, T1, T2, out);
}